// Round 15
// baseline (87.376 us; speedup 1.0000x reference)
//
#include <hip/hip_runtime.h>
#include <hip/hip_fp16.h>
#include <math.h>

#define MPTS 2048
#define NBATCH 8
#define NT 32            // MPTS / 64 candidates per lane (16 packed u32)
#define KMAX 64
#define NBIN 128         // bins per metric = q >> 9
#define BCAP 24          // rank-bin capture capacity
#define TPB 512          // 8 waves = 4 points x 2 metrics

typedef unsigned short u16;
typedef unsigned int u32;
typedef unsigned long long u64;

static __device__ __forceinline__ int mbcnt64(u64 m) {
  return __builtin_amdgcn_mbcnt_hi((u32)(m >> 32),
                                   __builtin_amdgcn_mbcnt_lo((u32)m, 0));
}

static __device__ __forceinline__ u32 packh2(float a, float b) {
  __half2 h = __floats2half2_rn(a, b);
  return *reinterpret_cast<u32*>(&h);
}
static __device__ __forceinline__ float2 unpackh2(u32 w) {
  __half2 h = *reinterpret_cast<__half2*>(&w);
  return __half22float2(h);
}

// q = clamp((int)(a * 65534/R2), 65535): u16 fixed-point distance.
// q == 65535 -> outside radius (sentinel). quantum ~3e-6 (below f32 noise).
static __device__ __forceinline__ u32 quantd(float a, float sc16) {
  const int qi = (int)(a * sc16);
  return (u32)(qi > 65535 ? 65535 : qi);
}

// Kernel A, metric-split: wave = (point, metric). metric 0: tau3 + 3D nbr list;
// metric 1: tau6 + x_centers. Whole batch staged in LDS (x.y/x.z half2).
// Distances quantized to u16 (2/u32 -> dq[16], total regs <= 64 -> 8 waves/SIMD).
// Exact top-64 threshold via integer 128-bin LDS histogram + rank-select.
template <bool COMPACT>
__global__ __launch_bounds__(TPB, 8) void kernelA(
    const float* __restrict__ x, const float* __restrict__ pos,
    float4* __restrict__ xci, float* __restrict__ tau3, u16* __restrict__ nbr) {
  __shared__ __align__(16) float4 P4[MPTS];        // 32 KB (pos.xyz, x.x)
  __shared__ __align__(16) u32 XH[MPTS];           //  8 KB (half2: x.y, x.z)
  __shared__ __align__(16) u32 histAll[8 * NBIN];  //  4 KB
  // per-wave region (128 u32) reuse after scan: hw[0]=bcnt, hw[1..24]=bv,
  // hw[25..56]=lst (64 x u16)

  const int tid  = threadIdx.x;
  const int wv   = tid >> 6;
  const int lane = tid & 63;
  const int pt   = wv >> 1;          // 0..3
  const int mtr  = wv & 1;           // 0 = 3D, 1 = 6D
  const int wid  = blockIdx.x * 4 + pt;        // global point id
  const int b    = wid >> 11;
  const int i    = wid & (MPTS - 1);
  const float* posb = pos + b * MPTS * 3;
  const float* xb   = x   + b * MPTS * 3;

  // cooperative stage of the whole batch
  for (int p = tid; p < MPTS; p += TPB) {
    P4[p] = make_float4(posb[3*p+0], posb[3*p+1], posb[3*p+2], xb[3*p+0]);
    XH[p] = packh2(xb[3*p+1], xb[3*p+2]);
  }
  ((uint2*)histAll)[tid] = make_uint2(0u, 0u);   // zero all 8*128 bins
  __syncthreads();

  u32* hw = &histAll[wv * NBIN];                 // per-wave private

  const float4 pi4 = P4[i];
  const float2 xi2 = unpackh2(XH[i]);
  const float2 c0 = make_float2(pi4.x, pi4.y);   // (pix, piy)
  const float2 c1 = make_float2(pi4.z, pi4.w);   // (piz, xix)
  const float2 c2 = xi2;                          // (xiy, xiz)

  const float SC3 = 65534.0f / 0.16f;
  const float SC6 = 65534.0f / 0.2025f;

  // --- pass 1: distances -> u16 quantized (packed pairs) + histogram
  u32 dq[NT / 2];
  if (mtr == 0) {
#pragma unroll
    for (int k2 = 0; k2 < NT / 2; ++k2) {
      const int j = (2 * k2) * 64 + lane;
      const float4 pa = P4[j];
      const float4 pb = P4[j + 64];
      const float2 e0 = make_float2(pa.x, pa.y) - c0;
      const float2 e1 = make_float2(pb.x, pb.y) - c0;
      const float dza = pa.z - pi4.z, dzb = pb.z - pi4.z;
      const float2 s0 = e0 * e0, s1 = e1 * e1;
      const float a0 = s0.x + s0.y + dza * dza;
      const float a1 = s1.x + s1.y + dzb * dzb;
      const u32 q0 = quantd(a0, SC3), q1 = quantd(a1, SC3);
      dq[k2] = q0 | (q1 << 16);
      if (q0 < 65535u) atomicAdd(&hw[q0 >> 9], 1u);
      if (q1 < 65535u) atomicAdd(&hw[q1 >> 9], 1u);
    }
  } else {
#pragma unroll
    for (int k2 = 0; k2 < NT / 2; ++k2) {
      const int j = (2 * k2) * 64 + lane;
      const float4 pa = P4[j];
      const float4 pb = P4[j + 64];
      const float2 xa = unpackh2(XH[j]);
      const float2 xcb = unpackh2(XH[j + 64]);
      const float2 a00 = make_float2(pa.x, pa.y) - c0;
      const float2 a01 = make_float2(pa.z, pa.w) - c1;
      const float2 a02 = xa - c2;
      float2 sa = a00 * a00; sa += a01 * a01; sa += a02 * a02;
      const float2 b00 = make_float2(pb.x, pb.y) - c0;
      const float2 b01 = make_float2(pb.z, pb.w) - c1;
      const float2 b02 = xcb - c2;
      float2 sb = b00 * b00; sb += b01 * b01; sb += b02 * b02;
      const u32 q0 = quantd(sa.x + sa.y, SC6), q1 = quantd(sb.x + sb.y, SC6);
      dq[k2] = q0 | (q1 << 16);
      if (q0 < 65535u) atomicAdd(&hw[q0 >> 9], 1u);
      if (q1 < 65535u) atomicAdd(&hw[q1 >> 9], 1u);
    }
  }

  // --- scan: lane owns bins 2*lane, 2*lane+1 (own wave's atomics: in-order)
  const u32 h0 = hw[2*lane], h1 = hw[2*lane+1];
  const u32 s2 = h0 + h1;
  u32 incl = s2;
#pragma unroll
  for (int off = 1; off < 64; off <<= 1) {
    const u32 tt = __shfl_up(incl, off, 64);
    if (lane >= off) incl += tt;
  }
  const u32 tot = __shfl(incl, 63, 64);
  u32 qt = 65534u;                   // no truncation: everything within R2

  if (tot > 64u) {
    const u32 excl = incl - s2;
    const u64 m = __ballot((excl < 64u) && (incl >= 64u));
    const int L = __builtin_ctzll(m);
    const u32 c0b = __shfl(excl, L, 64);
    const u32 g0 = __shfl(h0, L, 64);
    const u32 g1 = __shfl(h1, L, 64);
    int B; u32 cb, n;
    if (c0b + g0 >= 64u) { B = 2*L;     cb = c0b;      n = g0; }
    else                 { B = 2*L + 1; cb = c0b + g0; n = g1; }

    // hist region now dead -> reuse: hw[0]=bcnt, hw[1..]=bv
    if (lane == 0) hw[0] = 0u;
    u32* bv = &hw[1];

    // compact bin-B members (expected ~3, <=BCAP with huge margin)
#pragma unroll
    for (int k2 = 0; k2 < NT / 2; ++k2) {
      const u32 q0 = dq[k2] & 0xFFFFu, q1 = dq[k2] >> 16;
      if (q0 < 65535u && (int)(q0 >> 9) == B) {
        const u32 s = atomicAdd(&hw[0], 1u);
        if (s < (u32)BCAP) bv[s] = q0;
      }
      if (q1 < 65535u && (int)(q1 >> 9) == B) {
        const u32 s = atomicAdd(&hw[0], 1u);
        if (s < (u32)BCAP) bv[s] = q1;
      }
    }

    if (n <= (u32)BCAP) {
      // stable rank-select the (64-cb)-th smallest (integer, value-determ.)
      const int nn = (int)n;
      const u32 v = (lane < nn) ? bv[lane] : 0xFFFFFFFFu;
      u32 rank = 0;
      for (int cc = 0; cc < nn; ++cc) {
        const u32 w = __shfl(v, cc, 64);
        rank += ((w < v) || (w == v && cc < lane)) ? 1u : 0u;
      }
      const u64 sm = __ballot((lane < nn) && (rank == (u32)(63 - (int)cb)));
      qt = __shfl(v, __builtin_ctzll(sm), 64);
    } else {
      // bin overflow (P ~ 1e-15): take bin upper edge (few-neighbor slack)
      qt = (u32)((B << 9) + 511);
    }
  }

  // --- pass 2: ballot-compact the selected set (<=64, index-ordered = stable)
  u16* lw = (u16*)&hw[1 + BCAP];     // 64 x u16 in reused hist space
  const u32 qr0 = mtr ? 7281u : 4095u;    // ring bounds in q-space
  const u32 qr1 = mtr ? 20226u : 16383u;
  int base = 0;
#pragma unroll
  for (int k2 = 0; k2 < NT / 2; ++k2) {
    const u32 q0 = dq[k2] & 0xFFFFu, q1 = dq[k2] >> 16;
    {
      const int j = (2 * k2) * 64 + lane;
      const bool sel = (q0 <= qt);
      const u64 m = __ballot(sel);
      const int s = base + mbcnt64(m);
      if (sel && s < KMAX) {
        const int cl = (q0 > qr0) + (q0 > qr1);
        lw[s] = (u16)(j | (cl << 11));
      }
      base += __popcll(m);
    }
    {
      const int j = (2 * k2 + 1) * 64 + lane;
      const bool sel = (q1 <= qt);
      const u64 m = __ballot(sel);
      const int s = base + mbcnt64(m);
      if (sel && s < KMAX) {
        const int cl = (q1 > qr0) + (q1 > qr1);
        lw[s] = (u16)(j | (cl << 11));
      }
      base += __popcll(m);
    }
  }
  const int cn = base < KMAX ? base : KMAX;

  if (mtr == 0) {
    // 3D: neighbor list -> global (coalesced), tau3 for the fallback path
    if (COMPACT)
      nbr[(size_t)wid * KMAX + lane] = (lane < cn) ? lw[lane] : (u16)(3u << 11);
    if (lane == 0) tau3[wid] = ((float)qt + 1.0f) * (0.16f / 65534.0f);
  } else {
    // 6D: masked means -> x_centers, one gather + predication + packed reduce
    const u16 e = (lane < cn) ? lw[lane] : (u16)0xFFFF;   // cl=3 pad
    const int cl = (e >> 11) & 3;
    const int jj = e & (MPTS - 1);
    const float xjx = P4[jj].w;
    const float2 xj = unpackh2(XH[jj]);
    const bool v2 = (cl <= 2), v1 = (cl <= 1), v0 = (cl == 0);

    float2 v2a[6];
    v2a[0] = v0 ? make_float2(xjx, xj.x) : make_float2(0.f, 0.f);
    v2a[1] = v0 ? make_float2(xj.y, 1.f) : make_float2(0.f, 0.f);
    v2a[2] = v1 ? make_float2(xjx, xj.x) : make_float2(0.f, 0.f);
    v2a[3] = v1 ? make_float2(xj.y, 1.f) : make_float2(0.f, 0.f);
    v2a[4] = v2 ? make_float2(xjx, xj.x) : make_float2(0.f, 0.f);
    v2a[5] = v2 ? make_float2(xj.y, 1.f) : make_float2(0.f, 0.f);

#pragma unroll
    for (int v = 0; v < 6; ++v)
#pragma unroll
      for (int off = 32; off > 0; off >>= 1) {
        float2 o;
        o.x = __shfl_xor(v2a[v].x, off, 64);
        o.y = __shfl_xor(v2a[v].y, off, 64);
        v2a[v] += o;                                      // pk_add
      }

    if (lane == 0) {
#pragma unroll
      for (int s = 0; s < 3; ++s) {
        const float inv = 1.f / v2a[2*s+1].y;   // self always selected -> n >= 1
        xci[(size_t)wid * 3 + s] =
            make_float4(v2a[2*s].x * inv, v2a[2*s].y * inv, v2a[2*s+1].x * inv, 0.f);
      }
    }
  }
}

// Kernel B (fast): one wave per point, lane L handles neighbor slot L.
__global__ __launch_bounds__(256) void kernelB_fast(
    const float4* __restrict__ xci, const float* __restrict__ wlin,
    const float* __restrict__ blin, const u16* __restrict__ nbr,
    float* __restrict__ out) {
  const int wid  = (blockIdx.x * 256 + threadIdx.x) >> 6;  // global point id
  const int lane = threadIdx.x & 63;
  const int pbase = wid & ~(MPTS - 1);                     // batch start

  const u16 e = nbr[(size_t)wid * KMAX + lane];
  const int cl = e >> 11;
  const int gj = pbase + (e & (MPTS - 1));

  const float4 ci0 = xci[(size_t)wid*3 + 0];
  const float4 ci1 = xci[(size_t)wid*3 + 1];
  const float4 ci2 = xci[(size_t)wid*3 + 2];

  float s0 = 0.f, s1 = 0.f, s2 = 0.f, n0 = 0.f, n1 = 0.f, n2 = 0.f;
  if (cl <= 2) {
    const float4 cj2 = xci[(size_t)gj*3 + 2];
    float ux = ci2.x - cj2.x, uy = ci2.y - cj2.y, uz = ci2.z - cj2.z;
    s2 = sqrtf(fmaxf(ux*ux + uy*uy + uz*uz, 1e-12f)); n2 = 1.f;
    if (cl <= 1) {
      const float4 cj1 = xci[(size_t)gj*3 + 1];
      ux = ci1.x - cj1.x; uy = ci1.y - cj1.y; uz = ci1.z - cj1.z;
      s1 = sqrtf(fmaxf(ux*ux + uy*uy + uz*uz, 1e-12f)); n1 = 1.f;
      if (cl == 0) {
        const float4 cj0 = xci[(size_t)gj*3 + 0];
        ux = ci0.x - cj0.x; uy = ci0.y - cj0.y; uz = ci0.z - cj0.z;
        s0 = sqrtf(fmaxf(ux*ux + uy*uy + uz*uz, 1e-12f)); n0 = 1.f;
      }
    }
  }

  float vals[6] = {s0, s1, s2, n0, n1, n2};
#pragma unroll
  for (int v = 0; v < 6; ++v)
#pragma unroll
    for (int off = 32; off > 0; off >>= 1)
      vals[v] += __shfl_xor(vals[v], off, 64);

  if (lane == 0) {
    const float msg0 = vals[0] / vals[3];
    const float msg1 = vals[1] / vals[4];
    const float msg2 = vals[2] / vals[5];
    const float z = wlin[0]*msg0 + wlin[1]*msg1 + wlin[2]*msg2 + blin[0];
    out[wid] = 1.f / (1.f + expf(-z));
  }
}

// Kernel B (fallback, ws too small): full scan with tau3 thresholds.
__global__ __launch_bounds__(256) void kernelB_slow(
    const float* __restrict__ pos, const float* __restrict__ wlin,
    const float* __restrict__ blin, const float4* __restrict__ xci,
    const float* __restrict__ tau3, float* __restrict__ out) {
  const int wid  = (blockIdx.x * 256 + threadIdx.x) >> 6;
  const int lane = threadIdx.x & 63;
  const int b = wid >> 11;
  const int i = wid & (MPTS - 1);
  const float* posb = pos + b * MPTS * 3;
  const int pbase = b * MPTS;

  const float pix = posb[3*i+0], piy = posb[3*i+1], piz = posb[3*i+2];
  const float t3 = tau3[wid];
  const float thr0 = fminf(0.01f, t3);
  const float thr1 = fminf(0.04f, t3);

  const float4 ci0 = xci[(size_t)wid*3 + 0];
  const float4 ci1 = xci[(size_t)wid*3 + 1];
  const float4 ci2 = xci[(size_t)wid*3 + 2];

  float s0=0.f, s1=0.f, s2=0.f, n0=0.f, n1=0.f, n2=0.f;
  for (int k = 0; k < NT; ++k) {
    const int j = k * 64 + lane;
    const float dx = posb[3*j+0] - pix;
    const float dy = posb[3*j+1] - piy;
    const float dz = posb[3*j+2] - piz;
    const float a3 = dx*dx + dy*dy + dz*dz;
    if (a3 <= t3) {
      const float4 cj2 = xci[(size_t)(pbase + j)*3 + 2];
      float ux = ci2.x-cj2.x, uy = ci2.y-cj2.y, uz = ci2.z-cj2.z;
      s2 += sqrtf(fmaxf(ux*ux+uy*uy+uz*uz, 1e-12f)); n2 += 1.f;
      if (a3 <= thr1) {
        const float4 cj1 = xci[(size_t)(pbase + j)*3 + 1];
        ux = ci1.x-cj1.x; uy = ci1.y-cj1.y; uz = ci1.z-cj1.z;
        s1 += sqrtf(fmaxf(ux*ux+uy*uy+uz*uz, 1e-12f)); n1 += 1.f;
        if (a3 <= thr0) {
          const float4 cj0 = xci[(size_t)(pbase + j)*3 + 0];
          ux = ci0.x-cj0.x; uy = ci0.y-cj0.y; uz = ci0.z-cj0.z;
          s0 += sqrtf(fmaxf(ux*ux+uy*uy+uz*uz, 1e-12f)); n0 += 1.f;
        }
      }
    }
  }

  float vals[6] = {s0, s1, s2, n0, n1, n2};
#pragma unroll
  for (int v = 0; v < 6; ++v)
#pragma unroll
    for (int off = 32; off > 0; off >>= 1)
      vals[v] += __shfl_xor(vals[v], off, 64);

  if (lane == 0) {
    const float msg0 = vals[0] / vals[3];
    const float msg1 = vals[1] / vals[4];
    const float msg2 = vals[2] / vals[5];
    const float z = wlin[0]*msg0 + wlin[1]*msg1 + wlin[2]*msg2 + blin[0];
    out[wid] = 1.f / (1.f + expf(-z));
  }
}

extern "C" void kernel_launch(void* const* d_in, const int* in_sizes, int n_in,
                              void* d_out, int out_size, void* d_ws, size_t ws_size,
                              hipStream_t stream) {
  (void)in_sizes; (void)n_in; (void)out_size;
  const float* x    = (const float*)d_in[0];   // [8,2048,3]
  const float* pos  = (const float*)d_in[1];   // [8,2048,3]
  const float* wlin = (const float*)d_in[2];   // [1,3]
  const float* blin = (const float*)d_in[3];   // [1]
  float* out = (float*)d_out;

  const size_t npts = (size_t)NBATCH * MPTS;
  const size_t xci_bytes = npts * 3 * sizeof(float4);   // 786,432
  const size_t tau_bytes = npts * sizeof(float);        //  65,536
  const size_t nbr_bytes = npts * KMAX * sizeof(u16);   // 2,097,152
  float4* xci = (float4*)d_ws;
  float* tau3 = (float*)((char*)d_ws + xci_bytes);
  u16* nbr    = (u16*)((char*)d_ws + xci_bytes + tau_bytes);
  const bool fast = ws_size >= xci_bytes + tau_bytes + nbr_bytes;

  const int nblocksA = (int)(npts / 4);            // 4 points x 2 metric-waves
  const int nblocksB = (int)(npts * 64 / 256);
  if (fast) {
    kernelA<true><<<nblocksA, TPB, 0, stream>>>(x, pos, xci, tau3, nbr);
    kernelB_fast<<<nblocksB, 256, 0, stream>>>(xci, wlin, blin, nbr, out);
  } else {
    kernelA<false><<<nblocksA, TPB, 0, stream>>>(x, pos, xci, tau3, nbr);
    kernelB_slow<<<nblocksB, 256, 0, stream>>>(pos, wlin, blin, xci, tau3, out);
  }
}

// Round 16
// 80.749 us; speedup vs baseline: 1.0821x; 1.0821x over previous
//
#include <hip/hip_runtime.h>
#include <math.h>

#define MPTS 2048
#define NBATCH 8
#define NT 32            // candidates per lane (16 packed u32)
#define KMAX 64
#define NBIN 128         // bins per metric = q >> 9
#define BCAP 24          // rank-bin capture capacity
#define TPB 1024         // 16 waves = 8 points x 2 metrics

typedef unsigned short u16;
typedef unsigned int u32;
typedef unsigned long long u64;

static __device__ __forceinline__ int mbcnt64(u64 m) {
  return __builtin_amdgcn_mbcnt_hi((u32)(m >> 32),
                                   __builtin_amdgcn_mbcnt_lo((u32)m, 0));
}

// q = clamp((int)(a * 65534/R2), 65535): u16 fixed-point distance.
// q == 65535 -> outside radius (sentinel). quantum ~3e-6 (below f32 noise).
static __device__ __forceinline__ u32 quantd(float a, float sc16) {
  const int qi = (int)(a * sc16);
  return (u32)(qi > 65535 ? 65535 : qi);
}

// Kernel A, metric-split: wave = (point, metric); 8 points x 2 metrics per
// 1024-thread block share one LDS stage (amortized 2x vs TPB=512).
// Distances quantized to u16 pairs (dq[16] -> total regs <= 64 -> 8 waves/SIMD
// eligible); exact top-64 threshold via integer 128-bin LDS histogram +
// rank-select. metric 0: tau3 + 3D nbr list; metric 1: x_centers (3 scales).
template <bool COMPACT>
__global__ __launch_bounds__(TPB, 8) void kernelA(
    const float* __restrict__ x, const float* __restrict__ pos,
    float4* __restrict__ xci, float* __restrict__ tau3, u16* __restrict__ nbr) {
  __shared__ __align__(16) float4 P4[MPTS];         // 32 KB (pos.xyz, x.x)
  __shared__ __align__(16) float2 X2[MPTS];         // 16 KB (x.y, x.z)
  __shared__ __align__(16) u32 histAll[16 * NBIN];  //  8 KB
  // per-wave region (128 u32) reuse after scan: hw[0]=cnt, hw[1..24]=bv,
  // hw[25..56]=lst (64 x u16)

  const int tid  = threadIdx.x;
  const int wv   = tid >> 6;
  const int lane = tid & 63;
  const int pt   = wv >> 1;          // 0..7
  const int mtr  = wv & 1;           // 0 = 3D, 1 = 6D
  const int wid  = blockIdx.x * 8 + pt;        // global point id
  const int b    = wid >> 11;
  const int i    = wid & (MPTS - 1);
  const float* posb = pos + b * MPTS * 3;
  const float* xb   = x   + b * MPTS * 3;

  // cooperative stage of the whole batch (2 iterations)
  for (int p = tid; p < MPTS; p += TPB) {
    P4[p] = make_float4(posb[3*p+0], posb[3*p+1], posb[3*p+2], xb[3*p+0]);
    X2[p] = make_float2(xb[3*p+1], xb[3*p+2]);
  }
  ((uint2*)histAll)[tid] = make_uint2(0u, 0u);   // zero all 16*128 bins
  __syncthreads();

  u32* hw = &histAll[wv * NBIN];                 // per-wave private

  const float4 pi4 = P4[i];
  const float2 xi2 = X2[i];
  const float2 c0 = make_float2(pi4.x, pi4.y);   // (pix, piy)
  const float2 c1 = make_float2(pi4.z, pi4.w);   // (piz, xix)
  const float2 c2 = xi2;                          // (xiy, xiz)

  const float SC3 = 65534.0f / 0.16f;
  const float SC6 = 65534.0f / 0.2025f;

  // --- pass 1: distances -> u16 quantized (packed pairs) + histogram
  u32 dq[NT / 2];
  if (mtr == 0) {
#pragma unroll
    for (int k2 = 0; k2 < NT / 2; ++k2) {
      const int j = (2 * k2) * 64 + lane;
      const float4 pa = P4[j];
      const float4 pb = P4[j + 64];
      const float2 e0 = make_float2(pa.x, pa.y) - c0;
      const float2 e1 = make_float2(pb.x, pb.y) - c0;
      const float dza = pa.z - pi4.z, dzb = pb.z - pi4.z;
      const float2 s0 = e0 * e0, s1 = e1 * e1;
      const float a0 = s0.x + s0.y + dza * dza;
      const float a1 = s1.x + s1.y + dzb * dzb;
      const u32 q0 = quantd(a0, SC3), q1 = quantd(a1, SC3);
      dq[k2] = q0 | (q1 << 16);
      if (q0 < 65535u) atomicAdd(&hw[q0 >> 9], 1u);
      if (q1 < 65535u) atomicAdd(&hw[q1 >> 9], 1u);
    }
  } else {
#pragma unroll
    for (int k2 = 0; k2 < NT / 2; ++k2) {
      const int j = (2 * k2) * 64 + lane;
      const float4 pa = P4[j];
      const float4 pb = P4[j + 64];
      const float2 xa = X2[j];
      const float2 xcb = X2[j + 64];
      const float2 a00 = make_float2(pa.x, pa.y) - c0;
      const float2 a01 = make_float2(pa.z, pa.w) - c1;
      const float2 a02 = xa - c2;
      float2 sa = a00 * a00; sa += a01 * a01; sa += a02 * a02;
      const float2 b00 = make_float2(pb.x, pb.y) - c0;
      const float2 b01 = make_float2(pb.z, pb.w) - c1;
      const float2 b02 = xcb - c2;
      float2 sb = b00 * b00; sb += b01 * b01; sb += b02 * b02;
      const u32 q0 = quantd(sa.x + sa.y, SC6), q1 = quantd(sb.x + sb.y, SC6);
      dq[k2] = q0 | (q1 << 16);
      if (q0 < 65535u) atomicAdd(&hw[q0 >> 9], 1u);
      if (q1 < 65535u) atomicAdd(&hw[q1 >> 9], 1u);
    }
  }

  // --- scan: lane owns bins 2*lane, 2*lane+1 (own wave's atomics: in-order)
  const u32 h0 = hw[2*lane], h1 = hw[2*lane+1];
  const u32 s2 = h0 + h1;
  u32 incl = s2;
#pragma unroll
  for (int off = 1; off < 64; off <<= 1) {
    const u32 tt = __shfl_up(incl, off, 64);
    if (lane >= off) incl += tt;
  }
  const u32 tot = __shfl(incl, 63, 64);
  u32 qt = 65534u;                   // no truncation: everything within R2

  if (tot > 64u) {
    const u32 excl = incl - s2;
    const u64 m = __ballot((excl < 64u) && (incl >= 64u));
    const int L = __builtin_ctzll(m);
    const u32 c0b = __shfl(excl, L, 64);
    const u32 g0 = __shfl(h0, L, 64);
    const u32 g1 = __shfl(h1, L, 64);
    int B; u32 cb, n;
    if (c0b + g0 >= 64u) { B = 2*L;     cb = c0b;      n = g0; }
    else                 { B = 2*L + 1; cb = c0b + g0; n = g1; }

    // hist region now dead -> reuse: hw[0]=bcnt, hw[1..]=bv
    if (lane == 0) hw[0] = 0u;
    u32* bv = &hw[1];

    // compact bin-B members (expected ~3, <=BCAP with huge margin)
#pragma unroll
    for (int k2 = 0; k2 < NT / 2; ++k2) {
      const u32 q0 = dq[k2] & 0xFFFFu, q1 = dq[k2] >> 16;
      if (q0 < 65535u && (int)(q0 >> 9) == B) {
        const u32 s = atomicAdd(&hw[0], 1u);
        if (s < (u32)BCAP) bv[s] = q0;
      }
      if (q1 < 65535u && (int)(q1 >> 9) == B) {
        const u32 s = atomicAdd(&hw[0], 1u);
        if (s < (u32)BCAP) bv[s] = q1;
      }
    }

    if (n <= (u32)BCAP) {
      // stable rank-select the (64-cb)-th smallest (integer, value-determ.)
      const int nn = (int)n;
      const u32 v = (lane < nn) ? bv[lane] : 0xFFFFFFFFu;
      u32 rank = 0;
      for (int cc = 0; cc < nn; ++cc) {
        const u32 w = __shfl(v, cc, 64);
        rank += ((w < v) || (w == v && cc < lane)) ? 1u : 0u;
      }
      const u64 sm = __ballot((lane < nn) && (rank == (u32)(63 - (int)cb)));
      qt = __shfl(v, __builtin_ctzll(sm), 64);
    } else {
      // bin overflow (P ~ 1e-15): take bin upper edge (few-neighbor slack)
      qt = (u32)((B << 9) + 511);
    }
  }

  // --- pass 2: ballot-compact the selected set (<=64, index-ordered = stable)
  u16* lw = (u16*)&hw[1 + BCAP];     // 64 x u16 in reused hist space
  const u32 qr0 = mtr ? 7281u : 4095u;    // ring bounds in q-space
  const u32 qr1 = mtr ? 20226u : 16383u;
  int base = 0;
#pragma unroll
  for (int k2 = 0; k2 < NT / 2; ++k2) {
    const u32 q0 = dq[k2] & 0xFFFFu, q1 = dq[k2] >> 16;
    {
      const int j = (2 * k2) * 64 + lane;
      const bool sel = (q0 <= qt);
      const u64 m = __ballot(sel);
      const int s = base + mbcnt64(m);
      if (sel && s < KMAX) {
        const int cl = (q0 > qr0) + (q0 > qr1);
        lw[s] = (u16)(j | (cl << 11));
      }
      base += __popcll(m);
    }
    {
      const int j = (2 * k2 + 1) * 64 + lane;
      const bool sel = (q1 <= qt);
      const u64 m = __ballot(sel);
      const int s = base + mbcnt64(m);
      if (sel && s < KMAX) {
        const int cl = (q1 > qr0) + (q1 > qr1);
        lw[s] = (u16)(j | (cl << 11));
      }
      base += __popcll(m);
    }
  }
  const int cn = base < KMAX ? base : KMAX;

  if (mtr == 0) {
    // 3D: neighbor list -> global (coalesced), tau3 for the fallback path
    if (COMPACT)
      nbr[(size_t)wid * KMAX + lane] = (lane < cn) ? lw[lane] : (u16)(3u << 11);
    if (lane == 0) tau3[wid] = ((float)qt + 1.0f) * (0.16f / 65534.0f);
  } else {
    // 6D: masked means -> x_centers, one gather + predication + packed reduce
    const u16 e = (lane < cn) ? lw[lane] : (u16)0xFFFF;   // cl=3 pad
    const int cl = (e >> 11) & 3;
    const int jj = e & (MPTS - 1);
    const float xjx = P4[jj].w;
    const float2 xj = X2[jj];
    const bool v2 = (cl <= 2), v1 = (cl <= 1), v0 = (cl == 0);

    float2 v2a[6];
    v2a[0] = v0 ? make_float2(xjx, xj.x) : make_float2(0.f, 0.f);
    v2a[1] = v0 ? make_float2(xj.y, 1.f) : make_float2(0.f, 0.f);
    v2a[2] = v1 ? make_float2(xjx, xj.x) : make_float2(0.f, 0.f);
    v2a[3] = v1 ? make_float2(xj.y, 1.f) : make_float2(0.f, 0.f);
    v2a[4] = v2 ? make_float2(xjx, xj.x) : make_float2(0.f, 0.f);
    v2a[5] = v2 ? make_float2(xj.y, 1.f) : make_float2(0.f, 0.f);

#pragma unroll
    for (int v = 0; v < 6; ++v)
#pragma unroll
      for (int off = 32; off > 0; off >>= 1) {
        float2 o;
        o.x = __shfl_xor(v2a[v].x, off, 64);
        o.y = __shfl_xor(v2a[v].y, off, 64);
        v2a[v] += o;                                      // pk_add
      }

    if (lane == 0) {
#pragma unroll
      for (int s = 0; s < 3; ++s) {
        const float inv = 1.f / v2a[2*s+1].y;   // self always selected -> n >= 1
        xci[(size_t)wid * 3 + s] =
            make_float4(v2a[2*s].x * inv, v2a[2*s].y * inv, v2a[2*s+1].x * inv, 0.f);
      }
    }
  }
}

// Kernel B (fast): one wave per point, lane L handles neighbor slot L.
__global__ __launch_bounds__(256) void kernelB_fast(
    const float4* __restrict__ xci, const float* __restrict__ wlin,
    const float* __restrict__ blin, const u16* __restrict__ nbr,
    float* __restrict__ out) {
  const int wid  = (blockIdx.x * 256 + threadIdx.x) >> 6;  // global point id
  const int lane = threadIdx.x & 63;
  const int pbase = wid & ~(MPTS - 1);                     // batch start

  const u16 e = nbr[(size_t)wid * KMAX + lane];
  const int cl = e >> 11;
  const int gj = pbase + (e & (MPTS - 1));

  const float4 ci0 = xci[(size_t)wid*3 + 0];
  const float4 ci1 = xci[(size_t)wid*3 + 1];
  const float4 ci2 = xci[(size_t)wid*3 + 2];

  float s0 = 0.f, s1 = 0.f, s2 = 0.f, n0 = 0.f, n1 = 0.f, n2 = 0.f;
  if (cl <= 2) {
    const float4 cj2 = xci[(size_t)gj*3 + 2];
    float ux = ci2.x - cj2.x, uy = ci2.y - cj2.y, uz = ci2.z - cj2.z;
    s2 = sqrtf(fmaxf(ux*ux + uy*uy + uz*uz, 1e-12f)); n2 = 1.f;
    if (cl <= 1) {
      const float4 cj1 = xci[(size_t)gj*3 + 1];
      ux = ci1.x - cj1.x; uy = ci1.y - cj1.y; uz = ci1.z - cj1.z;
      s1 = sqrtf(fmaxf(ux*ux + uy*uy + uz*uz, 1e-12f)); n1 = 1.f;
      if (cl == 0) {
        const float4 cj0 = xci[(size_t)gj*3 + 0];
        ux = ci0.x - cj0.x; uy = ci0.y - cj0.y; uz = ci0.z - cj0.z;
        s0 = sqrtf(fmaxf(ux*ux + uy*uy + uz*uz, 1e-12f)); n0 = 1.f;
      }
    }
  }

  float vals[6] = {s0, s1, s2, n0, n1, n2};
#pragma unroll
  for (int v = 0; v < 6; ++v)
#pragma unroll
    for (int off = 32; off > 0; off >>= 1)
      vals[v] += __shfl_xor(vals[v], off, 64);

  if (lane == 0) {
    const float msg0 = vals[0] / vals[3];
    const float msg1 = vals[1] / vals[4];
    const float msg2 = vals[2] / vals[5];
    const float z = wlin[0]*msg0 + wlin[1]*msg1 + wlin[2]*msg2 + blin[0];
    out[wid] = 1.f / (1.f + expf(-z));
  }
}

// Kernel B (fallback, ws too small): full scan with tau3 thresholds.
__global__ __launch_bounds__(256) void kernelB_slow(
    const float* __restrict__ pos, const float* __restrict__ wlin,
    const float* __restrict__ blin, const float4* __restrict__ xci,
    const float* __restrict__ tau3, float* __restrict__ out) {
  const int wid  = (blockIdx.x * 256 + threadIdx.x) >> 6;
  const int lane = threadIdx.x & 63;
  const int b = wid >> 11;
  const int i = wid & (MPTS - 1);
  const float* posb = pos + b * MPTS * 3;
  const int pbase = b * MPTS;

  const float pix = posb[3*i+0], piy = posb[3*i+1], piz = posb[3*i+2];
  const float t3 = tau3[wid];
  const float thr0 = fminf(0.01f, t3);
  const float thr1 = fminf(0.04f, t3);

  const float4 ci0 = xci[(size_t)wid*3 + 0];
  const float4 ci1 = xci[(size_t)wid*3 + 1];
  const float4 ci2 = xci[(size_t)wid*3 + 2];

  float s0=0.f, s1=0.f, s2=0.f, n0=0.f, n1=0.f, n2=0.f;
  for (int k = 0; k < NT; ++k) {
    const int j = k * 64 + lane;
    const float dx = posb[3*j+0] - pix;
    const float dy = posb[3*j+1] - piy;
    const float dz = posb[3*j+2] - piz;
    const float a3 = dx*dx + dy*dy + dz*dz;
    if (a3 <= t3) {
      const float4 cj2 = xci[(size_t)(pbase + j)*3 + 2];
      float ux = ci2.x-cj2.x, uy = ci2.y-cj2.y, uz = ci2.z-cj2.z;
      s2 += sqrtf(fmaxf(ux*ux+uy*uy+uz*uz, 1e-12f)); n2 += 1.f;
      if (a3 <= thr1) {
        const float4 cj1 = xci[(size_t)(pbase + j)*3 + 1];
        ux = ci1.x-cj1.x; uy = ci1.y-cj1.y; uz = ci1.z-cj1.z;
        s1 += sqrtf(fmaxf(ux*ux+uy*uy+uz*uz, 1e-12f)); n1 += 1.f;
        if (a3 <= thr0) {
          const float4 cj0 = xci[(size_t)(pbase + j)*3 + 0];
          ux = ci0.x-cj0.x; uy = ci0.y-cj0.y; uz = ci0.z-cj0.z;
          s0 += sqrtf(fmaxf(ux*ux+uy*uy+uz*uz, 1e-12f)); n0 += 1.f;
        }
      }
    }
  }

  float vals[6] = {s0, s1, s2, n0, n1, n2};
#pragma unroll
  for (int v = 0; v < 6; ++v)
#pragma unroll
    for (int off = 32; off > 0; off >>= 1)
      vals[v] += __shfl_xor(vals[v], off, 64);

  if (lane == 0) {
    const float msg0 = vals[0] / vals[3];
    const float msg1 = vals[1] / vals[4];
    const float msg2 = vals[2] / vals[5];
    const float z = wlin[0]*msg0 + wlin[1]*msg1 + wlin[2]*msg2 + blin[0];
    out[wid] = 1.f / (1.f + expf(-z));
  }
}

extern "C" void kernel_launch(void* const* d_in, const int* in_sizes, int n_in,
                              void* d_out, int out_size, void* d_ws, size_t ws_size,
                              hipStream_t stream) {
  (void)in_sizes; (void)n_in; (void)out_size;
  const float* x    = (const float*)d_in[0];   // [8,2048,3]
  const float* pos  = (const float*)d_in[1];   // [8,2048,3]
  const float* wlin = (const float*)d_in[2];   // [1,3]
  const float* blin = (const float*)d_in[3];   // [1]
  float* out = (float*)d_out;

  const size_t npts = (size_t)NBATCH * MPTS;
  const size_t xci_bytes = npts * 3 * sizeof(float4);   // 786,432
  const size_t tau_bytes = npts * sizeof(float);        //  65,536
  const size_t nbr_bytes = npts * KMAX * sizeof(u16);   // 2,097,152
  float4* xci = (float4*)d_ws;
  float* tau3 = (float*)((char*)d_ws + xci_bytes);
  u16* nbr    = (u16*)((char*)d_ws + xci_bytes + tau_bytes);
  const bool fast = ws_size >= xci_bytes + tau_bytes + nbr_bytes;

  const int nblocksA = (int)(npts / 8);            // 8 points x 2 metric-waves
  const int nblocksB = (int)(npts * 64 / 256);
  if (fast) {
    kernelA<true><<<nblocksA, TPB, 0, stream>>>(x, pos, xci, tau3, nbr);
    kernelB_fast<<<nblocksB, 256, 0, stream>>>(xci, wlin, blin, nbr, out);
  } else {
    kernelA<false><<<nblocksA, TPB, 0, stream>>>(x, pos, xci, tau3, nbr);
    kernelB_slow<<<nblocksB, 256, 0, stream>>>(pos, wlin, blin, xci, tau3, out);
  }
}